// Round 3
// baseline (147.311 us; speedup 1.0000x reference)
//
#include <hip/hip_runtime.h>
#include <hip/hip_bf16.h>
#include <cstdint>
#include <cstddef>

#define TOKENS 8192
#define IN_F   1024
#define OUT_F  1024
#define KAUG   6144          // 1024 silu + 5*1024 jacobi (P0 folded into bias)
#define KB_    12288         // KAUG * 2 bytes (row stride of Aaug/Baug)
#define KCHUNK 3072          // split-K = 2
#define NT     96            // KCHUNK / 32 tiles per chunk (BK=32)

typedef __attribute__((ext_vector_type(4))) float          f32x4;
typedef __attribute__((ext_vector_type(4))) float          float4v;
typedef __attribute__((ext_vector_type(8))) __bf16         bf16x8;
typedef __attribute__((ext_vector_type(8))) unsigned short ushort8;

__device__ __forceinline__ unsigned short f2bf(float f) {
    unsigned int u = __builtin_bit_cast(unsigned int, f);
    u += 0x7FFFu + ((u >> 16) & 1u);
    return (unsigned short)(u >> 16);
}

// ============================================================================
// Kernel 1: augmented activations  A_aug[b][j*1024+i], j=0: silu, j=1..5: P_j
// ============================================================================
__global__ __launch_bounds__(256) void act_kernel(const float* __restrict__ x,
                                                  unsigned short* __restrict__ Aaug) {
    int gid = blockIdx.x * 256 + threadIdx.x;
    int b   = gid >> 7;
    int i8  = (gid & 127) << 3;

    const float* xp = x + (size_t)b * IN_F + i8;
    float xs[8];
    *(float4v*)&xs[0] = *(const float4v*)xp;
    *(float4v*)&xs[4] = *(const float4v*)(xp + 4);

    unsigned short res[6][8];
    #pragma unroll
    for (int e = 0; e < 8; ++e) {
        float v  = xs[e];
        float s  = v / (1.f + __expf(-v));
        float t  = tanhf(v);
        float p1 = 2.f * t;
        float p2 = (12.f / 24.f) * t * p1 - (8.f / 24.f) * 1.f;
        float p3 = (64.f / 120.f) * t * p2 - (48.f / 120.f) * p1;
        float p4 = (180.f / 336.f) * t * p3 - (144.f / 336.f) * p2;
        float p5 = (384.f / 720.f) * t * p4 - (320.f / 720.f) * p3;
        res[0][e] = f2bf(s);
        res[1][e] = f2bf(p1);
        res[2][e] = f2bf(p2);
        res[3][e] = f2bf(p3);
        res[4][e] = f2bf(p4);
        res[5][e] = f2bf(p5);
    }
    unsigned short* dst = Aaug + (size_t)b * KAUG + i8;
    #pragma unroll
    for (int j = 0; j < 6; ++j)
        *(ushort8*)(dst + j * IN_F) = *(const ushort8*)&res[j][0];
}

// ============================================================================
// Kernel 2: weight repack to bf16 [OUT_F][KAUG] + bias fold of P0 coeffs.
// ============================================================================
__global__ __launch_bounds__(256) void wt_kernel(const float* __restrict__ W,
                                                 const float* __restrict__ C,
                                                 const float* __restrict__ bias,
                                                 unsigned short* __restrict__ Baug,
                                                 float* __restrict__ bias_aug) {
    int o   = blockIdx.x;
    int tid = threadIdx.x;
    unsigned short* dst = Baug + (size_t)o * KAUG;
    float acc = 0.f;
    for (int i = tid; i < IN_F; i += 256) {
        float w = W[(size_t)o * IN_F + i];
        const float* c = C + ((size_t)o * IN_F + i) * 6;
        dst[i] = f2bf(w);
        #pragma unroll
        for (int j = 1; j < 6; ++j) dst[j * IN_F + i] = f2bf(c[j]);
        acc += c[0];
    }
    #pragma unroll
    for (int off = 32; off > 0; off >>= 1) acc += __shfl_down(acc, off, 64);
    __shared__ float red[4];
    int lane = tid & 63, wv = tid >> 6;
    if (lane == 0) red[wv] = acc;
    __syncthreads();
    if (tid == 0) bias_aug[o] = bias[o] + red[0] + red[1] + red[2] + red[3];
}

// ============================================================================
// Kernel 3: 256x256 bf16 GEMM, BK=32, 4-deep LDS pipeline, counted vmcnt(12).
//   split-K=2: chunk0 -> out partial, chunk1 -> P1 partial.
//   LDS 128KB = 4 buffers x [A 256x32 | B 256x32] bf16 (64B rows).
//   Swizzle: byte ^= ((row>>1)&3)<<4 on ds_read; inverse on global source;
//   gload_lds dest stays linear (rule 21).
// ============================================================================
__global__ __launch_bounds__(512, 2) void gemm_kernel(
    const unsigned short* __restrict__ A,   // [TOKENS][KAUG] bf16
    const unsigned short* __restrict__ B,   // [OUT_F][KAUG]  bf16
    float* __restrict__ out,                // chunk 0 partial
    float* __restrict__ P1)                 // chunk 1 partial
{
    __shared__ unsigned short lds[65536];   // 128 KB
    char* ldsc = (char*)lds;

    const int tid  = threadIdx.x;
    const int lane = tid & 63;
    const int wave = tid >> 6;              // 0..7
    const int wr   = wave >> 2;             // 0..1  (M)
    const int wc   = wave & 3;              // 0..3  (N)
    const int fr   = lane & 15;
    const int fg   = lane >> 4;
    const int wrbase = wr * 128;
    const int wcbase = wc * 64;

    // block decode: the 4 bn values sharing an A panel are adjacent in the
    // high bits -> land on the same XCD under round-robin-by-8 dispatch.
    const int bn    = blockIdx.x >> 6;        // 0..3
    const int bm    = (blockIdx.x >> 1) & 31; // 0..31
    const int chunk = blockIdx.x & 1;
    const int chunkoff = chunk * (KCHUNK * 2);   // bytes

    // ---- staging geometry (per thread): dest = linear tid*16 within region.
    // dest row r = j*128 + (tid>>2), dest slot = tid&3 (16B slots in 64B row).
    // source slot = destslot ^ ((r>>1)&3) = (tid&3) ^ ((tid>>3)&3).
    const int srow = tid >> 2;
    const int sswz = ((tid & 3) ^ ((tid >> 3) & 3)) << 4;
    const char* gA = (const char*)A + (size_t)(bm * 256 + srow) * KB_ + chunkoff + sswz;
    const char* gB = (const char*)B + (size_t)(bn * 256 + srow) * KB_ + chunkoff + sswz;

    // ---- ds_read: row*64 + ((fg*16) ^ (((row>>1)&3)<<4)); row&~15 alignment
    // makes the row-dependent term reduce to fr only.
    const int kcs = (fg << 4) ^ (((fr >> 1) & 3) << 4);

    f32x4 acc[8][4] = {};

#define STAGE(T) do {                                                          \
    const int _bo = ((T) & 3) * 32768;                                         \
    const int _ko = (T) * 64;                                                  \
    _Pragma("unroll")                                                          \
    for (int j_ = 0; j_ < 2; ++j_)                                             \
        __builtin_amdgcn_global_load_lds(                                      \
            (const __attribute__((address_space(1))) void*)(gA + (size_t)j_ * 128 * KB_ + _ko), \
            (__attribute__((address_space(3))) void*)(ldsc + _bo + j_ * 8192 + tid * 16), 16, 0, 0); \
    _Pragma("unroll")                                                          \
    for (int j_ = 0; j_ < 2; ++j_)                                             \
        __builtin_amdgcn_global_load_lds(                                      \
            (const __attribute__((address_space(1))) void*)(gB + (size_t)j_ * 128 * KB_ + _ko), \
            (__attribute__((address_space(3))) void*)(ldsc + _bo + 16384 + j_ * 8192 + tid * 16), 16, 0, 0); \
} while (0)

#define COMPUTE(T, CNT) do {                                                   \
    asm volatile("s_waitcnt vmcnt(" #CNT ")" ::: "memory");                    \
    __builtin_amdgcn_s_barrier();                                              \
    __builtin_amdgcn_sched_barrier(0);                                         \
    const char* _ab = ldsc + ((T) & 3) * 32768;                                \
    bf16x8 a_[8], b_[4];                                                       \
    _Pragma("unroll")                                                          \
    for (int mi_ = 0; mi_ < 8; ++mi_)                                          \
        a_[mi_] = *(const bf16x8*)(_ab + (wrbase + mi_ * 16 + fr) * 64 + kcs); \
    _Pragma("unroll")                                                          \
    for (int ni_ = 0; ni_ < 4; ++ni_)                                          \
        b_[ni_] = *(const bf16x8*)(_ab + 16384 + (wcbase + ni_ * 16 + fr) * 64 + kcs); \
    __builtin_amdgcn_s_setprio(1);                                             \
    _Pragma("unroll")                                                          \
    for (int mi_ = 0; mi_ < 8; ++mi_)                                          \
        _Pragma("unroll")                                                      \
        for (int ni_ = 0; ni_ < 4; ++ni_)                                      \
            acc[mi_][ni_] = __builtin_amdgcn_mfma_f32_16x16x32_bf16(           \
                a_[mi_], b_[ni_], acc[mi_][ni_], 0, 0, 0);                     \
    __builtin_amdgcn_s_setprio(0);                                             \
    __builtin_amdgcn_s_barrier();                                              \
} while (0)

    // prologue: fill 3 buffers ahead
    STAGE(0); STAGE(1); STAGE(2);

    // steady state: stage t+3, wait tile t (12 younger loads may fly)
    for (int t = 0; t < NT - 3; ++t) {
        STAGE(t + 3);
        COMPUTE(t, 12);
    }
    // tail: drain with decreasing counts
    COMPUTE(NT - 3, 8);
    COMPUTE(NT - 2, 4);
    COMPUTE(NT - 1, 0);
#undef COMPUTE
#undef STAGE

    // epilogue: D row=(lane>>4)*4+reg, col=lane&15
    float* dst = chunk ? P1 : out;
    #pragma unroll
    for (int mi = 0; mi < 8; ++mi) {
        #pragma unroll
        for (int ni = 0; ni < 4; ++ni) {
            const int col = bn * 256 + wcbase + ni * 16 + fr;
            #pragma unroll
            for (int rr = 0; rr < 4; ++rr) {
                const int row = bm * 256 + wrbase + mi * 16 + fg * 4 + rr;
                dst[(size_t)row * OUT_F + col] = acc[mi][ni][rr];
            }
        }
    }
}

// ============================================================================
// Kernel 4: out = out(chunk0) + P1(chunk1) + bias
// ============================================================================
__global__ __launch_bounds__(256) void reduce_kernel(float* __restrict__ out,
                                                     const float* __restrict__ P1,
                                                     const float* __restrict__ bias) {
    const int total = TOKENS * OUT_F / 4;
    const float4v* p1 = (const float4v*)P1;
    const float4v* bi = (const float4v*)bias;
    float4v*       o  = (float4v*)out;
    for (int i = blockIdx.x * 256 + threadIdx.x; i < total; i += gridDim.x * 256)
        o[i] = o[i] + p1[i] + bi[i & 255];
}

// ============================================================================
extern "C" void kernel_launch(void* const* d_in, const int* in_sizes, int n_in,
                              void* d_out, int out_size, void* d_ws, size_t ws_size,
                              hipStream_t stream) {
    const float* x    = (const float*)d_in[0];
    const float* W    = (const float*)d_in[1];
    const float* C    = (const float*)d_in[2];
    const float* bias = (const float*)d_in[3];
    float* out = (float*)d_out;

    char* ws = (char*)d_ws;
    const size_t a_bytes = (size_t)TOKENS * KAUG * 2;   // 100.7 MB
    const size_t b_bytes = (size_t)OUT_F * KAUG * 2;    // 12.6 MB
    unsigned short* Aaug     = (unsigned short*)ws;
    unsigned short* Baug     = (unsigned short*)(ws + a_bytes);
    float*          bias_aug = (float*)(ws + a_bytes + b_bytes);
    float*          P1       = (float*)(ws + a_bytes + b_bytes + 4096);

    hipLaunchKernelGGL(act_kernel, dim3(TOKENS * IN_F / 8 / 256), dim3(256), 0, stream,
                       x, Aaug);
    hipLaunchKernelGGL(wt_kernel, dim3(OUT_F), dim3(256), 0, stream,
                       W, C, bias, Baug, bias_aug);
    hipLaunchKernelGGL(gemm_kernel, dim3(256), dim3(512), 0, stream,
                       Aaug, Baug, out, P1);
    hipLaunchKernelGGL(reduce_kernel, dim3(2048), dim3(256), 0, stream,
                       out, P1, bias_aug);
}

// Round 4
// 145.276 us; speedup vs baseline: 1.0140x; 1.0140x over previous
//
#include <hip/hip_runtime.h>
#include <hip/hip_bf16.h>
#include <cstdint>
#include <cstddef>

#define TOKENS 8192
#define IN_F   1024
#define OUT_F  1024
#define KAUG   6144          // 1024 silu + 5*1024 jacobi (P0 folded into bias)
#define KB_    12288         // KAUG * 2 bytes (row stride of Aaug/Baug)
#define KCHUNK 3072          // split-K = 2
#define NT     48            // KCHUNK / 64 K-steps per chunk (BK=64)

typedef __attribute__((ext_vector_type(4))) float          f32x4;
typedef __attribute__((ext_vector_type(4))) float          float4v;
typedef __attribute__((ext_vector_type(8))) __bf16         bf16x8;
typedef __attribute__((ext_vector_type(8))) unsigned short ushort8;

__device__ __forceinline__ unsigned short f2bf(float f) {
    unsigned int u = __builtin_bit_cast(unsigned int, f);
    u += 0x7FFFu + ((u >> 16) & 1u);
    return (unsigned short)(u >> 16);
}

// ============================================================================
// Kernel 1: augmented activations  A_aug[b][j*1024+i], j=0: silu, j=1..5: P_j
// ============================================================================
__global__ __launch_bounds__(256) void act_kernel(const float* __restrict__ x,
                                                  unsigned short* __restrict__ Aaug) {
    int gid = blockIdx.x * 256 + threadIdx.x;
    int b   = gid >> 7;
    int i8  = (gid & 127) << 3;

    const float* xp = x + (size_t)b * IN_F + i8;
    float xs[8];
    *(float4v*)&xs[0] = *(const float4v*)xp;
    *(float4v*)&xs[4] = *(const float4v*)(xp + 4);

    unsigned short res[6][8];
    #pragma unroll
    for (int e = 0; e < 8; ++e) {
        float v  = xs[e];
        float s  = v / (1.f + __expf(-v));
        float t  = tanhf(v);
        float p1 = 2.f * t;
        float p2 = (12.f / 24.f) * t * p1 - (8.f / 24.f) * 1.f;
        float p3 = (64.f / 120.f) * t * p2 - (48.f / 120.f) * p1;
        float p4 = (180.f / 336.f) * t * p3 - (144.f / 336.f) * p2;
        float p5 = (384.f / 720.f) * t * p4 - (320.f / 720.f) * p3;
        res[0][e] = f2bf(s);
        res[1][e] = f2bf(p1);
        res[2][e] = f2bf(p2);
        res[3][e] = f2bf(p3);
        res[4][e] = f2bf(p4);
        res[5][e] = f2bf(p5);
    }
    unsigned short* dst = Aaug + (size_t)b * KAUG + i8;
    #pragma unroll
    for (int j = 0; j < 6; ++j)
        *(ushort8*)(dst + j * IN_F) = *(const ushort8*)&res[j][0];
}

// ============================================================================
// Kernel 2: weight repack to bf16 [OUT_F][KAUG] + bias fold of P0 coeffs.
// ============================================================================
__global__ __launch_bounds__(256) void wt_kernel(const float* __restrict__ W,
                                                 const float* __restrict__ C,
                                                 const float* __restrict__ bias,
                                                 unsigned short* __restrict__ Baug,
                                                 float* __restrict__ bias_aug) {
    int o   = blockIdx.x;
    int tid = threadIdx.x;
    unsigned short* dst = Baug + (size_t)o * KAUG;
    float acc = 0.f;
    for (int i = tid; i < IN_F; i += 256) {
        float w = W[(size_t)o * IN_F + i];
        const float* c = C + ((size_t)o * IN_F + i) * 6;
        dst[i] = f2bf(w);
        #pragma unroll
        for (int j = 1; j < 6; ++j) dst[j * IN_F + i] = f2bf(c[j]);
        acc += c[0];
    }
    #pragma unroll
    for (int off = 32; off > 0; off >>= 1) acc += __shfl_down(acc, off, 64);
    __shared__ float red[4];
    int lane = tid & 63, wv = tid >> 6;
    if (lane == 0) red[wv] = acc;
    __syncthreads();
    if (tid == 0) bias_aug[o] = bias[o] + red[0] + red[1] + red[2] + red[3];
}

// ============================================================================
// Kernel 3: 256x256x64 8-phase (4 phases/K-step) bf16 GEMM, split-K=2.
//   LDS 128KB = 2 bufs x [A 256x64 | B 256x64], st_16x32-swizzled columns
//   (linear gload_lds dest + inverse-swizzled global source + swizzled reads).
//   Per K-step T (buf = T&1):
//     ph1: 12 ds_read (a0 ks0, b ks0, a0 ks1)  | bar | lgkm(4) | 16 MFMA | bar
//     ph2: 12 ds_read (a1 ks0, b ks1, a1 ks1)  | bar | lgkm(0) | 16 MFMA | bar
//          (lgkm(0) => all reads of buf(T) done before any wave passes bar2)
//     ph3: stage A(T+2) -> buf(T&1)            | bar |         | 16 MFMA | bar
//     ph4: stage B(T+2), vmcnt(8)              | bar |         | 16 MFMA | bar
// ============================================================================
__global__ __launch_bounds__(512, 2) void gemm_kernel(
    const unsigned short* __restrict__ A,   // [TOKENS][KAUG] bf16
    const unsigned short* __restrict__ B,   // [OUT_F][KAUG]  bf16
    float* __restrict__ out,                // chunk 0 partial
    float* __restrict__ P1)                 // chunk 1 partial
{
    __shared__ unsigned short lds[65536];   // 128 KB
    char* ldsc = (char*)lds;

    const int tid  = threadIdx.x;
    const int lane = tid & 63;
    const int wave = tid >> 6;              // 0..7
    const int wr   = wave >> 2;             // 0..1  (M)
    const int wc   = wave & 3;              // 0..3  (N)
    const int fr   = lane & 15;
    const int fg   = lane >> 4;
    const int wrbase = wr * 128;
    const int wcbase = wc * 64;

    const int bn    = blockIdx.x >> 6;        // 0..3
    const int bm    = (blockIdx.x >> 1) & 31; // 0..31
    const int chunk = blockIdx.x & 1;
    const int chunkoff = chunk * (KCHUNK * 2);   // bytes

    // staging: dest linear tid*16; dest row r = j*64 + (tid>>3);
    // source colbyte = (tid&7)*16 ^ ((r&7)<<4), r&7 == (tid>>3)&7.
    const int r0  = tid >> 3;
    const int scb = ((tid & 7) * 16) ^ ((r0 & 7) << 4);
    const char* gA = (const char*)A + (size_t)(bm * 256 + r0) * KB_ + chunkoff + scb;
    const char* gB = (const char*)B + (size_t)(bn * 256 + r0) * KB_ + chunkoff + scb;

    // ds_read swizzled column-byte offsets (row&7 == fr&7)
    const int kcs0 = (fg * 16) ^ ((fr & 7) << 4);
    const int kcs1 = kcs0 ^ 64;

    f32x4 acc[8][4] = {};

#define STAGE_A(T2) do {                                                        \
    const int    _bo = ((T2) & 1) * 65536;                                      \
    const size_t _ko = (size_t)(T2) * 128;                                      \
    _Pragma("unroll")                                                           \
    for (int j_ = 0; j_ < 4; ++j_)                                              \
        __builtin_amdgcn_global_load_lds(                                       \
            (const __attribute__((address_space(1))) void*)(gA + (size_t)j_ * 64 * KB_ + _ko), \
            (__attribute__((address_space(3))) void*)(ldsc + _bo + j_ * 8192 + tid * 16), 16, 0, 0); \
} while (0)

#define STAGE_B(T2) do {                                                        \
    const int    _bo = ((T2) & 1) * 65536 + 32768;                              \
    const size_t _ko = (size_t)(T2) * 128;                                      \
    _Pragma("unroll")                                                           \
    for (int j_ = 0; j_ < 4; ++j_)                                              \
        __builtin_amdgcn_global_load_lds(                                       \
            (const __attribute__((address_space(1))) void*)(gB + (size_t)j_ * 64 * KB_ + _ko), \
            (__attribute__((address_space(3))) void*)(ldsc + _bo + j_ * 8192 + tid * 16), 16, 0, 0); \
} while (0)

#define MFMA16(MIH, AFR, BFR) do {                                              \
    __builtin_amdgcn_s_setprio(1);                                              \
    _Pragma("unroll")                                                           \
    for (int mi_ = 0; mi_ < 4; ++mi_)                                           \
        _Pragma("unroll")                                                       \
        for (int ni_ = 0; ni_ < 4; ++ni_)                                       \
            acc[(MIH) * 4 + mi_][ni_] = __builtin_amdgcn_mfma_f32_16x16x32_bf16( \
                AFR[mi_], BFR[ni_], acc[(MIH) * 4 + mi_][ni_], 0, 0, 0);        \
    __builtin_amdgcn_s_setprio(0);                                              \
} while (0)

#define TILE(T, ST, CNT) do {                                                   \
    const char* _ab = ldsc + ((T) & 1) * 65536;                                 \
    const char* _bb = _ab + 32768;                                              \
    bf16x8 a0k0_[4], a1k0_[4], a0k1_[4], a1k1_[4], b0_[4], b1_[4];              \
    /* ---- phase 1 window: 12 ds_read ---- */                                  \
    _Pragma("unroll")                                                           \
    for (int i_ = 0; i_ < 4; ++i_)                                              \
        a0k0_[i_] = *(const bf16x8*)(_ab + (wrbase + i_ * 16 + fr) * 128 + kcs0); \
    _Pragma("unroll")                                                           \
    for (int i_ = 0; i_ < 4; ++i_)                                              \
        b0_[i_]   = *(const bf16x8*)(_bb + (wcbase + i_ * 16 + fr) * 128 + kcs0); \
    _Pragma("unroll")                                                           \
    for (int i_ = 0; i_ < 4; ++i_)                                              \
        a0k1_[i_] = *(const bf16x8*)(_ab + (wrbase + i_ * 16 + fr) * 128 + kcs1); \
    __builtin_amdgcn_s_barrier();                                               \
    asm volatile("s_waitcnt lgkmcnt(4)" ::: "memory");                          \
    MFMA16(0, a0k0_, b0_);                                                      \
    __builtin_amdgcn_s_barrier();                                               \
    /* ---- phase 2 window: 12 ds_read, full lgkm drain ---- */                 \
    _Pragma("unroll")                                                           \
    for (int i_ = 0; i_ < 4; ++i_)                                              \
        a1k0_[i_] = *(const bf16x8*)(_ab + (wrbase + 64 + i_ * 16 + fr) * 128 + kcs0); \
    _Pragma("unroll")                                                           \
    for (int i_ = 0; i_ < 4; ++i_)                                              \
        b1_[i_]   = *(const bf16x8*)(_bb + (wcbase + i_ * 16 + fr) * 128 + kcs1); \
    _Pragma("unroll")                                                           \
    for (int i_ = 0; i_ < 4; ++i_)                                              \
        a1k1_[i_] = *(const bf16x8*)(_ab + (wrbase + 64 + i_ * 16 + fr) * 128 + kcs1); \
    __builtin_amdgcn_s_barrier();                                               \
    asm volatile("s_waitcnt lgkmcnt(0)" ::: "memory");                          \
    MFMA16(1, a1k0_, b0_);                                                      \
    __builtin_amdgcn_s_barrier();                                               \
    /* ---- phase 3 window: stage A(T+2) into buf(T&1) ---- */                  \
    if (ST) STAGE_A((T) + 2);                                                   \
    __builtin_amdgcn_s_barrier();                                               \
    MFMA16(0, a0k1_, b1_);                                                      \
    __builtin_amdgcn_s_barrier();                                               \
    /* ---- phase 4 window: stage B(T+2), counted vmcnt ---- */                 \
    if (ST) STAGE_B((T) + 2);                                                   \
    asm volatile("s_waitcnt vmcnt(" #CNT ")" ::: "memory");                     \
    __builtin_amdgcn_s_barrier();                                               \
    MFMA16(1, a1k1_, b1_);                                                      \
    __builtin_amdgcn_s_barrier();                                               \
} while (0)

    // prologue: stage tiles 0 and 1; tile 0 must land, tile 1 may fly
    STAGE_A(0); STAGE_B(0);
    STAGE_A(1); STAGE_B(1);
    asm volatile("s_waitcnt vmcnt(8)" ::: "memory");
    __builtin_amdgcn_s_barrier();

    for (int t = 0; t < NT - 2; ++t) TILE(t, true, 8);
    TILE(NT - 2, false, 0);
    TILE(NT - 1, false, 0);
#undef TILE
#undef MFMA16
#undef STAGE_A
#undef STAGE_B

    // epilogue: D row=(lane>>4)*4+reg, col=lane&15
    float* dst = chunk ? P1 : out;
    #pragma unroll
    for (int mi = 0; mi < 8; ++mi) {
        #pragma unroll
        for (int ni = 0; ni < 4; ++ni) {
            const int col = bn * 256 + wcbase + ni * 16 + fr;
            #pragma unroll
            for (int rr = 0; rr < 4; ++rr) {
                const int row = bm * 256 + wrbase + mi * 16 + fg * 4 + rr;
                dst[(size_t)row * OUT_F + col] = acc[mi][ni][rr];
            }
        }
    }
}

// ============================================================================
// Kernel 4: out = out(chunk0) + P1(chunk1) + bias
// ============================================================================
__global__ __launch_bounds__(256) void reduce_kernel(float* __restrict__ out,
                                                     const float* __restrict__ P1,
                                                     const float* __restrict__ bias) {
    const int total = TOKENS * OUT_F / 4;
    const float4v* p1 = (const float4v*)P1;
    const float4v* bi = (const float4v*)bias;
    float4v*       o  = (float4v*)out;
    for (int i = blockIdx.x * 256 + threadIdx.x; i < total; i += gridDim.x * 256)
        o[i] = o[i] + p1[i] + bi[i & 255];
}

// ============================================================================
extern "C" void kernel_launch(void* const* d_in, const int* in_sizes, int n_in,
                              void* d_out, int out_size, void* d_ws, size_t ws_size,
                              hipStream_t stream) {
    const float* x    = (const float*)d_in[0];
    const float* W    = (const float*)d_in[1];
    const float* C    = (const float*)d_in[2];
    const float* bias = (const float*)d_in[3];
    float* out = (float*)d_out;

    char* ws = (char*)d_ws;
    const size_t a_bytes = (size_t)TOKENS * KAUG * 2;   // 100.7 MB
    const size_t b_bytes = (size_t)OUT_F * KAUG * 2;    // 12.6 MB
    unsigned short* Aaug     = (unsigned short*)ws;
    unsigned short* Baug     = (unsigned short*)(ws + a_bytes);
    float*          bias_aug = (float*)(ws + a_bytes + b_bytes);
    float*          P1       = (float*)(ws + a_bytes + b_bytes + 4096);

    hipLaunchKernelGGL(act_kernel, dim3(TOKENS * IN_F / 8 / 256), dim3(256), 0, stream,
                       x, Aaug);
    hipLaunchKernelGGL(wt_kernel, dim3(OUT_F), dim3(256), 0, stream,
                       W, C, bias, Baug, bias_aug);
    hipLaunchKernelGGL(gemm_kernel, dim3(256), dim3(512), 0, stream,
                       Aaug, Baug, out, P1);
    hipLaunchKernelGGL(reduce_kernel, dim3(2048), dim3(256), 0, stream,
                       out, P1, bias_aug);
}

// Round 5
// 141.886 us; speedup vs baseline: 1.0382x; 1.0239x over previous
//
#include <hip/hip_runtime.h>
#include <hip/hip_bf16.h>
#include <cstdint>
#include <cstddef>

#define TOKENS 8192
#define IN_F   1024
#define OUT_F  1024
#define KAUG   6144          // 1024 silu + 5*1024 jacobi (P0 folded into bias)
#define KB_    12288         // KAUG * 2 bytes (row stride of Aaug/Baug)
#define KCHUNK 3072          // split-K = 2
#define NT     96            // KCHUNK / 32 K-steps per chunk (BK=32)

typedef __attribute__((ext_vector_type(4))) float          f32x4;
typedef __attribute__((ext_vector_type(4))) float          float4v;
typedef __attribute__((ext_vector_type(8))) __bf16         bf16x8;
typedef __attribute__((ext_vector_type(8))) unsigned short ushort8;

__device__ __forceinline__ unsigned short f2bf(float f) {
    unsigned int u = __builtin_bit_cast(unsigned int, f);
    u += 0x7FFFu + ((u >> 16) & 1u);
    return (unsigned short)(u >> 16);
}

// ============================================================================
// Kernel 1: augmented activations  A_aug[b][j*1024+i], j=0: silu, j=1..5: P_j
// ============================================================================
__global__ __launch_bounds__(256) void act_kernel(const float* __restrict__ x,
                                                  unsigned short* __restrict__ Aaug) {
    int gid = blockIdx.x * 256 + threadIdx.x;
    int b   = gid >> 7;
    int i8  = (gid & 127) << 3;

    const float* xp = x + (size_t)b * IN_F + i8;
    float xs[8];
    *(float4v*)&xs[0] = *(const float4v*)xp;
    *(float4v*)&xs[4] = *(const float4v*)(xp + 4);

    unsigned short res[6][8];
    #pragma unroll
    for (int e = 0; e < 8; ++e) {
        float v  = xs[e];
        float s  = v / (1.f + __expf(-v));
        float t  = tanhf(v);
        float p1 = 2.f * t;
        float p2 = (12.f / 24.f) * t * p1 - (8.f / 24.f) * 1.f;
        float p3 = (64.f / 120.f) * t * p2 - (48.f / 120.f) * p1;
        float p4 = (180.f / 336.f) * t * p3 - (144.f / 336.f) * p2;
        float p5 = (384.f / 720.f) * t * p4 - (320.f / 720.f) * p3;
        res[0][e] = f2bf(s);
        res[1][e] = f2bf(p1);
        res[2][e] = f2bf(p2);
        res[3][e] = f2bf(p3);
        res[4][e] = f2bf(p4);
        res[5][e] = f2bf(p5);
    }
    unsigned short* dst = Aaug + (size_t)b * KAUG + i8;
    #pragma unroll
    for (int j = 0; j < 6; ++j)
        *(ushort8*)(dst + j * IN_F) = *(const ushort8*)&res[j][0];
}

// ============================================================================
// Kernel 2: weight repack to bf16 [OUT_F][KAUG] + bias fold of P0 coeffs.
// ============================================================================
__global__ __launch_bounds__(256) void wt_kernel(const float* __restrict__ W,
                                                 const float* __restrict__ C,
                                                 const float* __restrict__ bias,
                                                 unsigned short* __restrict__ Baug,
                                                 float* __restrict__ bias_aug) {
    int o   = blockIdx.x;
    int tid = threadIdx.x;
    unsigned short* dst = Baug + (size_t)o * KAUG;
    float acc = 0.f;
    for (int i = tid; i < IN_F; i += 256) {
        float w = W[(size_t)o * IN_F + i];
        const float* c = C + ((size_t)o * IN_F + i) * 6;
        dst[i] = f2bf(w);
        #pragma unroll
        for (int j = 1; j < 6; ++j) dst[j * IN_F + i] = f2bf(c[j]);
        acc += c[0];
    }
    #pragma unroll
    for (int off = 32; off > 0; off >>= 1) acc += __shfl_down(acc, off, 64);
    __shared__ float red[4];
    int lane = tid & 63, wv = tid >> 6;
    if (lane == 0) red[wv] = acc;
    __syncthreads();
    if (tid == 0) bias_aug[o] = bias[o] + red[0] + red[1] + red[2] + red[3];
}

// ============================================================================
// Kernel 3: 256x256 bf16 GEMM, BK=32, 4 LDS buffers, 2 phases/K-step,
//   reads pipelined ONE PHASE AHEAD of consumption, counted lgkm/vmcnt.
//   split-K=2: chunk0 -> out partial, chunk1 -> P1 partial.
//   LDS 128KB = 4 bufs x [A 256x32 | B 256x32] bf16 (64B rows).
//   Tile T (buf T&3), stages tile T+3 (buf (T-1)&3  — provably drained):
//    ph1: [rd a47(T) x4 | stage A(T+3)] BAR lgkm(4) MFMA(mi0-3) vmcnt(6) BAR
//    ph2: [rd a03(T+1),b(T+1) x8 | stage B(T+3)] BAR lgkm(8) MFMA(mi4-7) BAR
//   vmcnt(6)+BAR at ph1-end makes buf(T+1) cross-wave-landed before ph2 reads.
// ============================================================================
__global__ __launch_bounds__(512, 2) void gemm_kernel(
    const unsigned short* __restrict__ A,   // [TOKENS][KAUG] bf16
    const unsigned short* __restrict__ B,   // [OUT_F][KAUG]  bf16
    float* __restrict__ out,                // chunk 0 partial
    float* __restrict__ P1)                 // chunk 1 partial
{
    __shared__ unsigned short lds[65536];   // 128 KB
    char* ldsc = (char*)lds;

    const int tid  = threadIdx.x;
    const int lane = tid & 63;
    const int wave = tid >> 6;              // 0..7
    const int wr   = wave >> 2;             // 0..1  (M)
    const int wc   = wave & 3;              // 0..3  (N)
    const int fr   = lane & 15;
    const int fg   = lane >> 4;
    const int wrbase = wr * 128;
    const int wcbase = wc * 64;

    const int bn    = blockIdx.x >> 6;        // 0..3
    const int bm    = (blockIdx.x >> 1) & 31; // 0..31
    const int chunk = blockIdx.x & 1;
    const int chunkoff = chunk * (KCHUNK * 2);   // bytes

    // staging: dest linear tid*16; dest row r = j*128 + (tid>>2), slot tid&3.
    // source slot = destslot ^ ((r>>1)&3) = (tid&3) ^ ((tid>>3)&3).
    const int srow = tid >> 2;
    const int sswz = ((tid & 3) ^ ((tid >> 3) & 3)) << 4;
    const char* gA = (const char*)A + (size_t)(bm * 256 + srow) * KB_ + chunkoff + sswz;
    const char* gB = (const char*)B + (size_t)(bn * 256 + srow) * KB_ + chunkoff + sswz;

    // ds_read swizzled column-byte offset within a 64B row.
    const int kcs = (fg << 4) ^ (((fr >> 1) & 3) << 4);

    f32x4 acc[8][4] = {};
    bf16x8 xa03[4], xa47[4], xb[4], ya03[4], ya47[4], yb[4];

#define STAGE_A(T3) do {                                                        \
    const int _bo = ((T3) & 3) * 32768;                                         \
    const size_t _ko = (size_t)(T3) * 64;                                       \
    _Pragma("unroll")                                                           \
    for (int j_ = 0; j_ < 2; ++j_)                                              \
        __builtin_amdgcn_global_load_lds(                                       \
            (const __attribute__((address_space(1))) void*)(gA + (size_t)j_ * 128 * KB_ + _ko), \
            (__attribute__((address_space(3))) void*)(ldsc + _bo + j_ * 8192 + tid * 16), 16, 0, 0); \
} while (0)

#define STAGE_B(T3) do {                                                        \
    const int _bo = ((T3) & 3) * 32768 + 16384;                                 \
    const size_t _ko = (size_t)(T3) * 64;                                       \
    _Pragma("unroll")                                                           \
    for (int j_ = 0; j_ < 2; ++j_)                                              \
        __builtin_amdgcn_global_load_lds(                                       \
            (const __attribute__((address_space(1))) void*)(gB + (size_t)j_ * 128 * KB_ + _ko), \
            (__attribute__((address_space(3))) void*)(ldsc + _bo + j_ * 8192 + tid * 16), 16, 0, 0); \
} while (0)

#define RD_A03(DST, BP) do {                                                    \
    _Pragma("unroll")                                                           \
    for (int i_ = 0; i_ < 4; ++i_)                                              \
        DST[i_] = *(const bf16x8*)((BP) + (wrbase + i_ * 16 + fr) * 64 + kcs);  \
} while (0)

#define RD_A47(DST, BP) do {                                                    \
    _Pragma("unroll")                                                           \
    for (int i_ = 0; i_ < 4; ++i_)                                              \
        DST[i_] = *(const bf16x8*)((BP) + (wrbase + 64 + i_ * 16 + fr) * 64 + kcs); \
} while (0)

#define RD_B(DST, BP) do {                                                      \
    _Pragma("unroll")                                                           \
    for (int i_ = 0; i_ < 4; ++i_)                                              \
        DST[i_] = *(const bf16x8*)((BP) + 16384 + (wcbase + i_ * 16 + fr) * 64 + kcs); \
} while (0)

#define MFMA16(H, AF, BF) do {                                                  \
    __builtin_amdgcn_s_setprio(1);                                              \
    _Pragma("unroll")                                                           \
    for (int mi_ = 0; mi_ < 4; ++mi_)                                           \
        _Pragma("unroll")                                                       \
        for (int ni_ = 0; ni_ < 4; ++ni_)                                       \
            acc[(H) * 4 + mi_][ni_] = __builtin_amdgcn_mfma_f32_16x16x32_bf16(  \
                AF[mi_], BF[ni_], acc[(H) * 4 + mi_][ni_], 0, 0, 0);            \
    __builtin_amdgcn_s_setprio(0);                                              \
} while (0)

#define TILE(T, CA03, CA47, CB, NA03, NB, STG, RD, CNT, LG) do {                \
    char* _bc = ldsc + ((T) & 3) * 32768;                                       \
    char* _bn = ldsc + (((T) + 1) & 3) * 32768;                                 \
    /* ---- phase 1 ---- */                                                     \
    RD_A47(CA47, _bc);                                                          \
    if (STG) STAGE_A((T) + 3);                                                  \
    __builtin_amdgcn_sched_barrier(0);                                          \
    __builtin_amdgcn_s_barrier();                                               \
    asm volatile("s_waitcnt lgkmcnt(4)" ::: "memory");                          \
    __builtin_amdgcn_sched_barrier(0);                                          \
    MFMA16(0, CA03, CB);                                                        \
    asm volatile("s_waitcnt vmcnt(" #CNT ")" ::: "memory");                     \
    __builtin_amdgcn_s_barrier();                                               \
    /* ---- phase 2 ---- */                                                     \
    if (RD) { RD_A03(NA03, _bn); RD_B(NB, _bn); }                               \
    if (STG) STAGE_B((T) + 3);                                                  \
    __builtin_amdgcn_sched_barrier(0);                                          \
    __builtin_amdgcn_s_barrier();                                               \
    asm volatile("s_waitcnt lgkmcnt(" #LG ")" ::: "memory");                    \
    __builtin_amdgcn_sched_barrier(0);                                          \
    MFMA16(1, CA47, CB);                                                        \
    __builtin_amdgcn_s_barrier();                                               \
} while (0)

    // prologue: stage tiles 0,1,2 (12 loads); own tile-0 done at vmcnt(8),
    // BAR makes it cross-wave; then pre-read tile-0 ph1 fragments.
    STAGE_A(0); STAGE_B(0);
    STAGE_A(1); STAGE_B(1);
    STAGE_A(2); STAGE_B(2);
    asm volatile("s_waitcnt vmcnt(8)" ::: "memory");
    __builtin_amdgcn_s_barrier();
    asm volatile("" ::: "memory");
    RD_A03(xa03, ldsc);
    RD_B(xb, ldsc);

    // steady state: tiles 0..91 in x/y pairs (all stage, vmcnt(6))
    for (int t = 0; t < NT - 4; t += 2) {
        TILE(t,     xa03, xa47, xb, ya03, yb, true, true, 6, 8);
        TILE(t + 1, ya03, ya47, yb, xa03, xb, true, true, 6, 8);
    }
    // tail: 92 stages tile 95; then drain
    TILE(92, xa03, xa47, xb, ya03, yb, true,  true,  6, 8);
    TILE(93, ya03, ya47, yb, xa03, xb, false, true,  4, 8);
    TILE(94, xa03, xa47, xb, ya03, yb, false, true,  0, 8);
    TILE(95, ya03, ya47, yb, xa03, xb, false, false, 0, 0);
#undef TILE
#undef MFMA16
#undef RD_B
#undef RD_A47
#undef RD_A03
#undef STAGE_B
#undef STAGE_A

    // epilogue: D row=(lane>>4)*4+reg, col=lane&15
    float* dst = chunk ? P1 : out;
    #pragma unroll
    for (int mi = 0; mi < 8; ++mi) {
        #pragma unroll
        for (int ni = 0; ni < 4; ++ni) {
            const int col = bn * 256 + wcbase + ni * 16 + fr;
            #pragma unroll
            for (int rr = 0; rr < 4; ++rr) {
                const int row = bm * 256 + wrbase + mi * 16 + fg * 4 + rr;
                dst[(size_t)row * OUT_F + col] = acc[mi][ni][rr];
            }
        }
    }
}

// ============================================================================
// Kernel 4: out = out(chunk0) + P1(chunk1) + bias
// ============================================================================
__global__ __launch_bounds__(256) void reduce_kernel(float* __restrict__ out,
                                                     const float* __restrict__ P1,
                                                     const float* __restrict__ bias) {
    const int total = TOKENS * OUT_F / 4;
    const float4v* p1 = (const float4v*)P1;
    const float4v* bi = (const float4v*)bias;
    float4v*       o  = (float4v*)out;
    for (int i = blockIdx.x * 256 + threadIdx.x; i < total; i += gridDim.x * 256)
        o[i] = o[i] + p1[i] + bi[i & 255];
}

// ============================================================================
extern "C" void kernel_launch(void* const* d_in, const int* in_sizes, int n_in,
                              void* d_out, int out_size, void* d_ws, size_t ws_size,
                              hipStream_t stream) {
    const float* x    = (const float*)d_in[0];
    const float* W    = (const float*)d_in[1];
    const float* C    = (const float*)d_in[2];
    const float* bias = (const float*)d_in[3];
    float* out = (float*)d_out;

    char* ws = (char*)d_ws;
    const size_t a_bytes = (size_t)TOKENS * KAUG * 2;   // 100.7 MB
    const size_t b_bytes = (size_t)OUT_F * KAUG * 2;    // 12.6 MB
    unsigned short* Aaug     = (unsigned short*)ws;
    unsigned short* Baug     = (unsigned short*)(ws + a_bytes);
    float*          bias_aug = (float*)(ws + a_bytes + b_bytes);
    float*          P1       = (float*)(ws + a_bytes + b_bytes + 4096);

    hipLaunchKernelGGL(act_kernel, dim3(TOKENS * IN_F / 8 / 256), dim3(256), 0, stream,
                       x, Aaug);
    hipLaunchKernelGGL(wt_kernel, dim3(OUT_F), dim3(256), 0, stream,
                       W, C, bias, Baug, bias_aug);
    hipLaunchKernelGGL(gemm_kernel, dim3(256), dim3(512), 0, stream,
                       Aaug, Baug, out, P1);
    hipLaunchKernelGGL(reduce_kernel, dim3(2048), dim3(256), 0, stream,
                       out, P1, bias_aug);
}

// Round 6
// 132.667 us; speedup vs baseline: 1.1104x; 1.0695x over previous
//
#include <hip/hip_runtime.h>
#include <hip/hip_bf16.h>
#include <cstdint>
#include <cstddef>

#define TOKENS 8192
#define IN_F   1024
#define OUT_F  1024
#define KAUG   6144          // 1024 silu + 5*1024 jacobi (P0 folded into bias)
#define KB_    12288         // KAUG * 2 bytes (row stride of Aaug/Baug)
#define NT     96            // KAUG / 64 K-tiles (BK=64, no split-K)
#define BUFSZ  49152         // A 256x64x2 (32KB) + B 128x64x2 (16KB)

typedef __attribute__((ext_vector_type(4))) float          f32x4;
typedef __attribute__((ext_vector_type(4))) float          float4v;
typedef __attribute__((ext_vector_type(8))) __bf16         bf16x8;
typedef __attribute__((ext_vector_type(8))) unsigned short ushort8;

__device__ __forceinline__ unsigned short f2bf(float f) {
    unsigned int u = __builtin_bit_cast(unsigned int, f);
    u += 0x7FFFu + ((u >> 16) & 1u);
    return (unsigned short)(u >> 16);
}

// ============================================================================
// Kernel 1: augmented activations  A_aug[b][j*1024+i], j=0: silu, j=1..5: P_j
// ============================================================================
__global__ __launch_bounds__(256) void act_kernel(const float* __restrict__ x,
                                                  unsigned short* __restrict__ Aaug) {
    int gid = blockIdx.x * 256 + threadIdx.x;
    int b   = gid >> 7;
    int i8  = (gid & 127) << 3;

    const float* xp = x + (size_t)b * IN_F + i8;
    float xs[8];
    *(float4v*)&xs[0] = *(const float4v*)xp;
    *(float4v*)&xs[4] = *(const float4v*)(xp + 4);

    unsigned short res[6][8];
    #pragma unroll
    for (int e = 0; e < 8; ++e) {
        float v  = xs[e];
        float s  = v / (1.f + __expf(-v));
        float t  = tanhf(v);
        float p1 = 2.f * t;
        float p2 = (12.f / 24.f) * t * p1 - (8.f / 24.f) * 1.f;
        float p3 = (64.f / 120.f) * t * p2 - (48.f / 120.f) * p1;
        float p4 = (180.f / 336.f) * t * p3 - (144.f / 336.f) * p2;
        float p5 = (384.f / 720.f) * t * p4 - (320.f / 720.f) * p3;
        res[0][e] = f2bf(s);
        res[1][e] = f2bf(p1);
        res[2][e] = f2bf(p2);
        res[3][e] = f2bf(p3);
        res[4][e] = f2bf(p4);
        res[5][e] = f2bf(p5);
    }
    unsigned short* dst = Aaug + (size_t)b * KAUG + i8;
    #pragma unroll
    for (int j = 0; j < 6; ++j)
        *(ushort8*)(dst + j * IN_F) = *(const ushort8*)&res[j][0];
}

// ============================================================================
// Kernel 2: weight repack to bf16 [OUT_F][KAUG] + bias fold of P0 coeffs.
// ============================================================================
__global__ __launch_bounds__(256) void wt_kernel(const float* __restrict__ W,
                                                 const float* __restrict__ C,
                                                 const float* __restrict__ bias,
                                                 unsigned short* __restrict__ Baug,
                                                 float* __restrict__ bias_aug) {
    int o   = blockIdx.x;
    int tid = threadIdx.x;
    unsigned short* dst = Baug + (size_t)o * KAUG;
    float acc = 0.f;
    for (int i = tid; i < IN_F; i += 256) {
        float w = W[(size_t)o * IN_F + i];
        const float* c = C + ((size_t)o * IN_F + i) * 6;
        dst[i] = f2bf(w);
        #pragma unroll
        for (int j = 1; j < 6; ++j) dst[j * IN_F + i] = f2bf(c[j]);
        acc += c[0];
    }
    #pragma unroll
    for (int off = 32; off > 0; off >>= 1) acc += __shfl_down(acc, off, 64);
    __shared__ float red[4];
    int lane = tid & 63, wv = tid >> 6;
    if (lane == 0) red[wv] = acc;
    __syncthreads();
    if (tid == 0) bias_aug[o] = bias[o] + red[0] + red[1] + red[2] + red[3];
}

// ============================================================================
// Kernel 3: 256x128 bf16 GEMM, BK=64, NO split-K, bias fused in epilogue.
//   8 waves as 4M x 2N -> wave-tile 64x64 (minimal LDS re-read: 128KB/BK64).
//   LDS 144KB = 3 bufs x [A 256x64 | B 128x64], zero-conflict XOR swizzle
//   (linear gload_lds dest + inverse-swizzled global source + swizzled reads).
//   Per tile T (buf T%3), 2 phases:
//    ph1: rd ks1 frags of T (8) | stage ALL of T+2 (6) | BAR lgkm(8)
//         | 16 MFMA (ks0) | vmcnt(6) BAR
//    ph2: rd ks0 frags of T+1 (8) | BAR lgkm(8) | 16 MFMA (ks1) | BAR
// ============================================================================
__global__ __launch_bounds__(512, 2) void gemm_kernel(
    const unsigned short* __restrict__ A,   // [TOKENS][KAUG] bf16
    const unsigned short* __restrict__ B,   // [OUT_F][KAUG]  bf16
    const float* __restrict__ bias_aug,     // [OUT_F]
    float* __restrict__ out)                // [TOKENS][OUT_F]
{
    __shared__ unsigned short lds[73728];   // 144 KB
    char* ldsc = (char*)lds;

    const int tid  = threadIdx.x;
    const int lane = tid & 63;
    const int wave = tid >> 6;              // 0..7
    const int wr   = wave >> 1;             // 0..3  (M)
    const int wc   = wave & 1;              // 0..1  (N)
    const int fr   = lane & 15;
    const int fg   = lane >> 4;
    const int wrbase = wr * 64;
    const int wcbase = wc * 64;

    // block decode: 4 bm values per XCD (B panel L2-resident per XCD)
    const int xcd = blockIdx.x & 7;
    const int idx = blockIdx.x >> 3;        // 0..31
    const int bm  = xcd * 4 + (idx & 3);    // 0..31
    const int bn  = idx >> 2;               // 0..7

    // staging: dest linear tid*16; dest row r = j*64 + (tid>>3);
    // source colbyte = (tid&7)*16 ^ ((r&7)<<4), r&7 == (tid>>3)&7.
    const int r0  = tid >> 3;
    const int scb = ((tid & 7) * 16) ^ ((r0 & 7) << 4);
    const char* gA = (const char*)A + (size_t)(bm * 256 + r0) * KB_ + scb;
    const char* gB = (const char*)B + (size_t)(bn * 128 + r0) * KB_ + scb;

    // ds_read swizzled column-byte offsets (row&7 == fr&7)
    const int kcs0 = (fg * 16) ^ ((fr & 7) << 4);
    const int kcs1 = kcs0 ^ 64;

    f32x4 acc[4][4] = {};
    bf16x8 xa0[4], xa1[4], xb0[4], xb1[4];
    bf16x8 ya0[4], ya1[4], yb0[4], yb1[4];

#define STAGE_AB(T2, BS) do {                                                   \
    const size_t _ko = (size_t)(T2) * 128;                                      \
    _Pragma("unroll")                                                           \
    for (int j_ = 0; j_ < 4; ++j_)                                              \
        __builtin_amdgcn_global_load_lds(                                       \
            (const __attribute__((address_space(1))) void*)(gA + (size_t)j_ * 64 * KB_ + _ko), \
            (__attribute__((address_space(3))) void*)(ldsc + (BS) + j_ * 8192 + tid * 16), 16, 0, 0); \
    _Pragma("unroll")                                                           \
    for (int j_ = 0; j_ < 2; ++j_)                                              \
        __builtin_amdgcn_global_load_lds(                                       \
            (const __attribute__((address_space(1))) void*)(gB + (size_t)j_ * 64 * KB_ + _ko), \
            (__attribute__((address_space(3))) void*)(ldsc + (BS) + 32768 + j_ * 8192 + tid * 16), 16, 0, 0); \
} while (0)

#define RD_A(DST, BO, KCS) do {                                                 \
    _Pragma("unroll")                                                           \
    for (int i_ = 0; i_ < 4; ++i_)                                              \
        DST[i_] = *(const bf16x8*)(ldsc + (BO) + (wrbase + i_ * 16 + fr) * 128 + (KCS)); \
} while (0)

#define RD_B(DST, BO, KCS) do {                                                 \
    _Pragma("unroll")                                                           \
    for (int i_ = 0; i_ < 4; ++i_)                                              \
        DST[i_] = *(const bf16x8*)(ldsc + (BO) + 32768 + (wcbase + i_ * 16 + fr) * 128 + (KCS)); \
} while (0)

#define MFMA16(AF, BF) do {                                                     \
    __builtin_amdgcn_s_setprio(1);                                              \
    _Pragma("unroll")                                                           \
    for (int mi_ = 0; mi_ < 4; ++mi_)                                           \
        _Pragma("unroll")                                                       \
        for (int ni_ = 0; ni_ < 4; ++ni_)                                       \
            acc[mi_][ni_] = __builtin_amdgcn_mfma_f32_16x16x32_bf16(            \
                AF[mi_], BF[ni_], acc[mi_][ni_], 0, 0, 0);                      \
    __builtin_amdgcn_s_setprio(0);                                              \
} while (0)

// BC=buf(T), BN_=buf(T+1), BS=buf(T+2); CA*/CB* current frags, NA0/NB0 next.
#define TILE(T, BC, BN_, BS, CA0, CA1, CB0, CB1, NA0, NB0, STG, RDN, CNT, LG2) do { \
    /* ---- phase 1 ---- */                                                     \
    RD_A(CA1, BC, kcs1);                                                        \
    RD_B(CB1, BC, kcs1);                                                        \
    if (STG) STAGE_AB((T) + 2, BS);                                             \
    __builtin_amdgcn_sched_barrier(0);                                          \
    __builtin_amdgcn_s_barrier();                                               \
    asm volatile("s_waitcnt lgkmcnt(8)" ::: "memory");                          \
    __builtin_amdgcn_sched_barrier(0);                                          \
    MFMA16(CA0, CB0);                                                           \
    asm volatile("s_waitcnt vmcnt(" #CNT ")" ::: "memory");                     \
    __builtin_amdgcn_s_barrier();                                               \
    /* ---- phase 2 ---- */                                                     \
    if (RDN) { RD_A(NA0, BN_, kcs0); RD_B(NB0, BN_, kcs0); }                    \
    __builtin_amdgcn_sched_barrier(0);                                          \
    __builtin_amdgcn_s_barrier();                                               \
    asm volatile("s_waitcnt lgkmcnt(" #LG2 ")" ::: "memory");                   \
    __builtin_amdgcn_sched_barrier(0);                                          \
    MFMA16(CA1, CB1);                                                           \
    __builtin_amdgcn_s_barrier();                                               \
} while (0)

    // prologue: stage tiles 0 (buf0) and 1 (buf1); tile0 must land (allow
    // tile1's 6 in flight); BAR -> cross-wave; pre-read tile-0 ks0 frags.
    STAGE_AB(0, 0);
    STAGE_AB(1, BUFSZ);
    asm volatile("s_waitcnt vmcnt(6)" ::: "memory");
    __builtin_amdgcn_s_barrier();
    RD_A(xa0, 0, kcs0);
    RD_B(xb0, 0, kcs0);

    // steady state: 6-tile groups (buf period 3 x frag ping-pong 2)
    for (int t = 0; t < 90; t += 6) {
        TILE(t + 0, 0 * BUFSZ, 1 * BUFSZ, 2 * BUFSZ, xa0, xa1, xb0, xb1, ya0, yb0, true, true, 6, 8);
        TILE(t + 1, 1 * BUFSZ, 2 * BUFSZ, 0 * BUFSZ, ya0, ya1, yb0, yb1, xa0, xb0, true, true, 6, 8);
        TILE(t + 2, 2 * BUFSZ, 0 * BUFSZ, 1 * BUFSZ, xa0, xa1, xb0, xb1, ya0, yb0, true, true, 6, 8);
        TILE(t + 3, 0 * BUFSZ, 1 * BUFSZ, 2 * BUFSZ, ya0, ya1, yb0, yb1, xa0, xb0, true, true, 6, 8);
        TILE(t + 4, 1 * BUFSZ, 2 * BUFSZ, 0 * BUFSZ, xa0, xa1, xb0, xb1, ya0, yb0, true, true, 6, 8);
        TILE(t + 5, 2 * BUFSZ, 0 * BUFSZ, 1 * BUFSZ, ya0, ya1, yb0, yb1, xa0, xb0, true, true, 6, 8);
    }
    // tail: tiles 90..95 (95 staged at 93; 94/95 drain; 95 reads no next)
    TILE(90, 0 * BUFSZ, 1 * BUFSZ, 2 * BUFSZ, xa0, xa1, xb0, xb1, ya0, yb0, true,  true,  6, 8);
    TILE(91, 1 * BUFSZ, 2 * BUFSZ, 0 * BUFSZ, ya0, ya1, yb0, yb1, xa0, xb0, true,  true,  6, 8);
    TILE(92, 2 * BUFSZ, 0 * BUFSZ, 1 * BUFSZ, xa0, xa1, xb0, xb1, ya0, yb0, true,  true,  6, 8);
    TILE(93, 0 * BUFSZ, 1 * BUFSZ, 2 * BUFSZ, ya0, ya1, yb0, yb1, xa0, xb0, true,  true,  6, 8);
    TILE(94, 1 * BUFSZ, 2 * BUFSZ, 0 * BUFSZ, xa0, xa1, xb0, xb1, ya0, yb0, false, true,  0, 8);
    TILE(95, 2 * BUFSZ, 0 * BUFSZ, 1 * BUFSZ, ya0, ya1, yb0, yb1, xa0, xb0, false, false, 0, 0);
#undef TILE
#undef MFMA16
#undef RD_B
#undef RD_A
#undef STAGE_AB

    // epilogue: D row=(lane>>4)*4+reg, col=lane&15 ; + bias
    #pragma unroll
    for (int ni = 0; ni < 4; ++ni) {
        const int col = bn * 128 + wcbase + ni * 16 + fr;
        const float bv = bias_aug[col];
        #pragma unroll
        for (int mi = 0; mi < 4; ++mi) {
            #pragma unroll
            for (int rr = 0; rr < 4; ++rr) {
                const int row = bm * 256 + wrbase + mi * 16 + fg * 4 + rr;
                out[(size_t)row * OUT_F + col] = acc[mi][ni][rr] + bv;
            }
        }
    }
}

// ============================================================================
extern "C" void kernel_launch(void* const* d_in, const int* in_sizes, int n_in,
                              void* d_out, int out_size, void* d_ws, size_t ws_size,
                              hipStream_t stream) {
    const float* x    = (const float*)d_in[0];
    const float* W    = (const float*)d_in[1];
    const float* C    = (const float*)d_in[2];
    const float* bias = (const float*)d_in[3];
    float* out = (float*)d_out;

    char* ws = (char*)d_ws;
    const size_t a_bytes = (size_t)TOKENS * KAUG * 2;   // 100.7 MB
    const size_t b_bytes = (size_t)OUT_F * KAUG * 2;    // 12.6 MB
    unsigned short* Aaug     = (unsigned short*)ws;
    unsigned short* Baug     = (unsigned short*)(ws + a_bytes);
    float*          bias_aug = (float*)(ws + a_bytes + b_bytes);

    hipLaunchKernelGGL(act_kernel, dim3(TOKENS * IN_F / 8 / 256), dim3(256), 0, stream,
                       x, Aaug);
    hipLaunchKernelGGL(wt_kernel, dim3(OUT_F), dim3(256), 0, stream,
                       W, C, bias, Baug, bias_aug);
    hipLaunchKernelGGL(gemm_kernel, dim3(256), dim3(512), 0, stream,
                       Aaug, Baug, bias_aug, out);
}

// Round 7
// 100.319 us; speedup vs baseline: 1.4684x; 1.3225x over previous
//
#include <hip/hip_runtime.h>
#include <hip/hip_bf16.h>
#include <cstdint>
#include <cstddef>

#define TOKENS 8192
#define IN_F   1024
#define OUT_F  1024
#define NTOT   112           // 80 i8 tiles (K=5120) + 32 bf16 tiles (K=1024)
#define NI8    80
#define BUFSZ  24576         // A 256x64B (16KB) + B 128x64B (8KB)
#define B1     24576
#define B2     49152
#define PSTR   5120          // Pi8/Ci8 row stride bytes
#define ASTR   2048          // Ab16/Wb16 row stride bytes

typedef __attribute__((ext_vector_type(4))) float          f32x4;
typedef __attribute__((ext_vector_type(4))) float          float4v;
typedef __attribute__((ext_vector_type(4))) int            i32x4;
typedef __attribute__((ext_vector_type(8))) __bf16         bf16x8;
typedef __attribute__((ext_vector_type(8))) unsigned short ushort8;
typedef __attribute__((ext_vector_type(8))) char           char8;

__device__ __forceinline__ unsigned short f2bf(float f) {
    unsigned int u = __builtin_bit_cast(unsigned int, f);
    u += 0x7FFFu + ((u >> 16) & 1u);
    return (unsigned short)(u >> 16);
}

// ============================================================================
// Kernel 1: activations. silu -> bf16 Ab16[b][1024]; P1..P5 -> i8 (x63.5)
// Pi8[b][(k-1)*1024 + i], row stride 5120.
// ============================================================================
__global__ __launch_bounds__(256) void act_kernel(const float* __restrict__ x,
                                                  unsigned short* __restrict__ Ab16,
                                                  char* __restrict__ Pi8) {
    int gid = blockIdx.x * 256 + threadIdx.x;
    int b   = gid >> 7;
    int i8  = (gid & 127) << 3;

    const float* xp = x + (size_t)b * IN_F + i8;
    float xs[8];
    *(float4v*)&xs[0] = *(const float4v*)xp;
    *(float4v*)&xs[4] = *(const float4v*)(xp + 4);

    unsigned short sres[8];
    char8 q[5];
    #pragma unroll
    for (int e = 0; e < 8; ++e) {
        float v  = xs[e];
        float s  = v / (1.f + __expf(-v));
        float t  = tanhf(v);
        float p1 = 2.f * t;
        float p2 = (12.f / 24.f) * t * p1 - (8.f / 24.f) * 1.f;
        float p3 = (64.f / 120.f) * t * p2 - (48.f / 120.f) * p1;
        float p4 = (180.f / 336.f) * t * p3 - (144.f / 336.f) * p2;
        float p5 = (384.f / 720.f) * t * p4 - (320.f / 720.f) * p3;
        sres[e] = f2bf(s);
        q[0][e] = (char)__float2int_rn(p1 * 63.5f);
        q[1][e] = (char)__float2int_rn(p2 * 63.5f);
        q[2][e] = (char)__float2int_rn(p3 * 63.5f);
        q[3][e] = (char)__float2int_rn(p4 * 63.5f);
        q[4][e] = (char)__float2int_rn(p5 * 63.5f);
    }
    *(ushort8*)(Ab16 + (size_t)b * IN_F + i8) = *(const ushort8*)&sres[0];
    char* pd = Pi8 + (size_t)b * PSTR + i8;
    #pragma unroll
    for (int k = 0; k < 5; ++k)
        *(char8*)(pd + k * 1024) = q[k];
}

// ============================================================================
// Kernel 2: weights. W -> bf16 Wb16[o][1024]; C k=1..5 -> i8 with per-row
// scale (absmax/127) -> Ci8[o][5120], scaleC[o]; k=0 folded into bias_aug.
// ============================================================================
__global__ __launch_bounds__(256) void wt_kernel(const float* __restrict__ W,
                                                 const float* __restrict__ C,
                                                 const float* __restrict__ bias,
                                                 unsigned short* __restrict__ Wb16,
                                                 char* __restrict__ Ci8,
                                                 float* __restrict__ scaleC,
                                                 float* __restrict__ bias_aug) {
    int o   = blockIdx.x;
    int tid = threadIdx.x;
    float cv[4][5];
    float biasacc = 0.f, amax = 0.f;
    #pragma unroll
    for (int j = 0; j < 4; ++j) {
        int i = tid + j * 256;
        Wb16[(size_t)o * IN_F + i] = f2bf(W[(size_t)o * IN_F + i]);
        const float* c = C + ((size_t)o * IN_F + i) * 6;
        biasacc += c[0];
        #pragma unroll
        for (int k = 0; k < 5; ++k) {
            float v = c[k + 1];
            cv[j][k] = v;
            amax = fmaxf(amax, fabsf(v));
        }
    }
    #pragma unroll
    for (int off = 32; off > 0; off >>= 1) {
        biasacc += __shfl_down(biasacc, off, 64);
        amax = fmaxf(amax, __shfl_down(amax, off, 64));
    }
    __shared__ float redS[4], redM[4];
    int lane = tid & 63, wv = tid >> 6;
    if (lane == 0) { redS[wv] = biasacc; redM[wv] = amax; }
    __syncthreads();
    float rA = fmaxf(fmaxf(redM[0], redM[1]), fmaxf(redM[2], redM[3]));
    rA = fmaxf(rA, 1e-20f);
    float rinv = 127.f / rA;
    if (tid == 0) {
        scaleC[o]   = rA / 127.f;
        bias_aug[o] = bias[o] + redS[0] + redS[1] + redS[2] + redS[3];
    }
    char* dst = Ci8 + (size_t)o * PSTR;
    #pragma unroll
    for (int j = 0; j < 4; ++j) {
        int i = tid + j * 256;
        #pragma unroll
        for (int k = 0; k < 5; ++k)
            dst[k * 1024 + i] = (char)__float2int_rn(cv[j][k] * rinv);
    }
}

// ============================================================================
// Kernel 3: fused GEMM, 256x128 tile, 4 waves (wave-tile 128x64).
//   Tiles 0..79: i8 K=5120 (mfma_i32_16x16x64_i8, accI).
//   Dequant: accF = accI * scaleC[col]/63.5.
//   Tiles 80..111: bf16 K=1024 (mfma_f32_16x16x32_bf16 into accF).
//   LDS 72KB = 3 bufs x 24KB (64B rows), zero-conflict XOR swizzle
//   (linear gload_lds dest + inverse-swizzled source + swizzled ds_read).
//   2-phase/tile, reads one phase ahead, stage T+2 in ph1(A)/ph2(B),
//   counted vmcnt(4)/lgkm(4,8).
// ============================================================================
__global__ __launch_bounds__(256, 1) void gemm_kernel(
    const char* __restrict__ Pi8,
    const unsigned short* __restrict__ Ab16,
    const char* __restrict__ Ci8,
    const unsigned short* __restrict__ Wb16,
    const float* __restrict__ scaleC,
    const float* __restrict__ bias_aug,
    float* __restrict__ out)
{
    __shared__ __align__(16) char ldsc[73728];   // 72 KB

    const int tid  = threadIdx.x;
    const int lane = tid & 63;
    const int wave = tid >> 6;              // 0..3
    const int wr   = wave >> 1;             // 0..1 (M)
    const int wc   = wave & 1;              // 0..1 (N)
    const int fr   = lane & 15;
    const int fg   = lane >> 4;
    const int wrbase = wr * 128;
    const int wcbase = wc * 64;

    const int xcd = blockIdx.x & 7;
    const int idx = blockIdx.x >> 3;        // 0..31
    const int bm  = xcd * 4 + (idx & 3);    // 0..31
    const int bn  = idx >> 2;               // 0..7

    // staging: dest = linear tid*16 per 4KB chunk (64 rows of 64B);
    // dest row r = chunk*64 + (tid>>2), slot = tid&3;
    // source slot = (tid&3) ^ ((r>>1)&3) = (tid&3) ^ ((tid>>3)&3).
    const int r0   = tid >> 2;
    const int sswz = ((tid & 3) ^ ((tid >> 3) & 3)) << 4;
    const char* gA8  = Pi8 + (size_t)(bm * 256 + r0) * PSTR + sswz;
    const char* gB8  = Ci8 + (size_t)(bn * 128 + r0) * PSTR + sswz;
    const char* gA16 = (const char*)Ab16 + (size_t)(bm * 256 + r0) * ASTR + sswz;
    const char* gB16 = (const char*)Wb16 + (size_t)(bn * 128 + r0) * ASTR + sswz;

    // ds_read swizzled slot within 64B row ((row>>1)&3 == (fr>>1)&3)
    const int kcs = (fg << 4) ^ (((fr >> 1) & 3) << 4);

    i32x4 accI[8][4] = {};
    f32x4 accF[8][4];
    i32x4 xa03[4], xa47[4], xb[4], ya03[4], ya47[4], yb[4];

    // per-lane dequant scales
    float sc_[4];
    #pragma unroll
    for (int ni = 0; ni < 4; ++ni)
        sc_[ni] = scaleC[bn * 128 + wcbase + ni * 16 + fr] * (1.f / 63.5f);

#define GLDS(SRC, DST) __builtin_amdgcn_global_load_lds(                        \
    (const __attribute__((address_space(1))) void*)(SRC),                       \
    (__attribute__((address_space(3))) void*)(DST), 16, 0, 0)

#define STAGE_AI(S, BO) do { const char* s_ = gA8 + (size_t)(S) * 64;           \
    char* d_ = ldsc + (BO) + tid * 16;                                          \
    GLDS(s_, d_); GLDS(s_ + (size_t)64 * PSTR, d_ + 4096);                      \
    GLDS(s_ + (size_t)128 * PSTR, d_ + 8192);                                   \
    GLDS(s_ + (size_t)192 * PSTR, d_ + 12288); } while (0)
#define STAGE_BI(S, BO) do { const char* s_ = gB8 + (size_t)(S) * 64;           \
    char* d_ = ldsc + (BO) + 16384 + tid * 16;                                  \
    GLDS(s_, d_); GLDS(s_ + (size_t)64 * PSTR, d_ + 4096); } while (0)
#define STAGE_AF(S, BO) do { const char* s_ = gA16 + (size_t)((S) - NI8) * 64;  \
    char* d_ = ldsc + (BO) + tid * 16;                                          \
    GLDS(s_, d_); GLDS(s_ + (size_t)64 * ASTR, d_ + 4096);                      \
    GLDS(s_ + (size_t)128 * ASTR, d_ + 8192);                                   \
    GLDS(s_ + (size_t)192 * ASTR, d_ + 12288); } while (0)
#define STAGE_BF(S, BO) do { const char* s_ = gB16 + (size_t)((S) - NI8) * 64;  \
    char* d_ = ldsc + (BO) + 16384 + tid * 16;                                  \
    GLDS(s_, d_); GLDS(s_ + (size_t)64 * ASTR, d_ + 4096); } while (0)

#define RD_A03(DST, BO) do { _Pragma("unroll")                                  \
    for (int i_ = 0; i_ < 4; ++i_)                                              \
        DST[i_] = *(const i32x4*)(ldsc + (BO) + (wrbase + i_ * 16 + fr) * 64 + kcs); } while (0)
#define RD_A47(DST, BO) do { _Pragma("unroll")                                  \
    for (int i_ = 0; i_ < 4; ++i_)                                              \
        DST[i_] = *(const i32x4*)(ldsc + (BO) + (wrbase + 64 + i_ * 16 + fr) * 64 + kcs); } while (0)
#define RD_B(DST, BO) do { _Pragma("unroll")                                    \
    for (int i_ = 0; i_ < 4; ++i_)                                              \
        DST[i_] = *(const i32x4*)(ldsc + (BO) + 16384 + (wcbase + i_ * 16 + fr) * 64 + kcs); } while (0)

#define MFI(H, AF, BF) do { __builtin_amdgcn_s_setprio(1);                      \
    _Pragma("unroll")                                                           \
    for (int mi_ = 0; mi_ < 4; ++mi_)                                           \
        _Pragma("unroll")                                                       \
        for (int ni_ = 0; ni_ < 4; ++ni_)                                       \
            accI[(H) * 4 + mi_][ni_] = __builtin_amdgcn_mfma_i32_16x16x64_i8(   \
                AF[mi_], BF[ni_], accI[(H) * 4 + mi_][ni_], 0, 0, 0);           \
    __builtin_amdgcn_s_setprio(0); } while (0)

#define MFF(H, AF, BF) do { __builtin_amdgcn_s_setprio(1);                      \
    _Pragma("unroll")                                                           \
    for (int mi_ = 0; mi_ < 4; ++mi_)                                           \
        _Pragma("unroll")                                                       \
        for (int ni_ = 0; ni_ < 4; ++ni_)                                       \
            accF[(H) * 4 + mi_][ni_] = __builtin_amdgcn_mfma_f32_16x16x32_bf16( \
                __builtin_bit_cast(bf16x8, AF[mi_]),                            \
                __builtin_bit_cast(bf16x8, BF[ni_]),                            \
                accF[(H) * 4 + mi_][ni_], 0, 0, 0);                             \
    __builtin_amdgcn_s_setprio(0); } while (0)

#define TILE(T, BC, BN2, BS, MF, CA03, CA47, CB, NA03, NB, SA, SB, DOST, RDN, CNT, LG2) do { \
    /* phase 1 */                                                               \
    RD_A47(CA47, BC);                                                           \
    if (DOST) SA((T) + 2, BS);                                                  \
    __builtin_amdgcn_sched_barrier(0);                                          \
    __builtin_amdgcn_s_barrier();                                               \
    asm volatile("s_waitcnt lgkmcnt(4)" ::: "memory");                          \
    __builtin_amdgcn_sched_barrier(0);                                          \
    MF(0, CA03, CB);                                                            \
    asm volatile("s_waitcnt vmcnt(" #CNT ")" ::: "memory");                     \
    __builtin_amdgcn_s_barrier();                                               \
    /* phase 2 */                                                               \
    if (RDN) { RD_A03(NA03, BN2); RD_B(NB, BN2); }                              \
    if (DOST) SB((T) + 2, BS);                                                  \
    __builtin_amdgcn_sched_barrier(0);                                          \
    __builtin_amdgcn_s_barrier();                                               \
    asm volatile("s_waitcnt lgkmcnt(" #LG2 ")" ::: "memory");                   \
    __builtin_amdgcn_sched_barrier(0);                                          \
    MF(1, CA47, CB);                                                            \
    __builtin_amdgcn_s_barrier();                                               \
} while (0)

    // prologue: stage tiles 0 (buf0), 1 (buf1); T0 must land; pre-read T0.
    STAGE_AI(0, 0); STAGE_BI(0, 0);
    STAGE_AI(1, B1); STAGE_BI(1, B1);
    asm volatile("s_waitcnt vmcnt(6)" ::: "memory");
    __builtin_amdgcn_s_barrier();
    RD_A03(xa03, 0);
    RD_B(xb, 0);

    // i8 segment: tiles 0..77
    for (int t = 0; t < 78; t += 6) {
        TILE(t + 0, 0,  B1, B2, MFI, xa03, xa47, xb, ya03, yb, STAGE_AI, STAGE_BI, 1, 1, 4, 8);
        TILE(t + 1, B1, B2, 0,  MFI, ya03, ya47, yb, xa03, xb, STAGE_AI, STAGE_BI, 1, 1, 4, 8);
        TILE(t + 2, B2, 0,  B1, MFI, xa03, xa47, xb, ya03, yb, STAGE_AI, STAGE_BI, 1, 1, 4, 8);
        TILE(t + 3, 0,  B1, B2, MFI, ya03, ya47, yb, xa03, xb, STAGE_AI, STAGE_BI, 1, 1, 4, 8);
        TILE(t + 4, B1, B2, 0,  MFI, xa03, xa47, xb, ya03, yb, STAGE_AI, STAGE_BI, 1, 1, 4, 8);
        TILE(t + 5, B2, 0,  B1, MFI, ya03, ya47, yb, xa03, xb, STAGE_AI, STAGE_BI, 1, 1, 4, 8);
    }
    // boundary: i8 compute, bf16 staging (tiles 80, 81)
    TILE(78, 0,  B1, B2, MFI, xa03, xa47, xb, ya03, yb, STAGE_AF, STAGE_BF, 1, 1, 4, 8);
    TILE(79, B1, B2, 0,  MFI, ya03, ya47, yb, xa03, xb, STAGE_AF, STAGE_BF, 1, 1, 4, 8);

    // dequantize: accF = accI * scaleC[col]/63.5
    #pragma unroll
    for (int mi = 0; mi < 8; ++mi)
        #pragma unroll
        for (int ni = 0; ni < 4; ++ni)
            #pragma unroll
            for (int rr = 0; rr < 4; ++rr)
                accF[mi][ni][rr] = (float)accI[mi][ni][rr] * sc_[ni];

    // bf16 segment: tiles 80..109
    for (int t = 80; t < 110; t += 6) {
        TILE(t + 0, B2, 0,  B1, MFF, xa03, xa47, xb, ya03, yb, STAGE_AF, STAGE_BF, 1, 1, 4, 8);
        TILE(t + 1, 0,  B1, B2, MFF, ya03, ya47, yb, xa03, xb, STAGE_AF, STAGE_BF, 1, 1, 4, 8);
        TILE(t + 2, B1, B2, 0,  MFF, xa03, xa47, xb, ya03, yb, STAGE_AF, STAGE_BF, 1, 1, 4, 8);
        TILE(t + 3, B2, 0,  B1, MFF, ya03, ya47, yb, xa03, xb, STAGE_AF, STAGE_BF, 1, 1, 4, 8);
        TILE(t + 4, 0,  B1, B2, MFF, xa03, xa47, xb, ya03, yb, STAGE_AF, STAGE_BF, 1, 1, 4, 8);
        TILE(t + 5, B1, B2, 0,  MFF, ya03, ya47, yb, xa03, xb, STAGE_AF, STAGE_BF, 1, 1, 4, 8);
    }
    TILE(110, B2, 0,  B1, MFF, xa03, xa47, xb, ya03, yb, STAGE_AF, STAGE_BF, 0, 1, 0, 8);
    TILE(111, 0,  B1, B2, MFF, ya03, ya47, yb, xa03, xb, STAGE_AF, STAGE_BF, 0, 0, 0, 0);

#undef TILE
#undef MFF
#undef MFI
#undef RD_B
#undef RD_A47
#undef RD_A03
#undef STAGE_BF
#undef STAGE_AF
#undef STAGE_BI
#undef STAGE_AI
#undef GLDS

    // epilogue: D row=(lane>>4)*4+reg, col=lane&15 ; + bias
    #pragma unroll
    for (int ni = 0; ni < 4; ++ni) {
        const int col = bn * 128 + wcbase + ni * 16 + fr;
        const float bv = bias_aug[col];
        #pragma unroll
        for (int mi = 0; mi < 8; ++mi) {
            #pragma unroll
            for (int rr = 0; rr < 4; ++rr) {
                const int row = bm * 256 + wrbase + mi * 16 + fg * 4 + rr;
                out[(size_t)row * OUT_F + col] = accF[mi][ni][rr] + bv;
            }
        }
    }
}

// ============================================================================
extern "C" void kernel_launch(void* const* d_in, const int* in_sizes, int n_in,
                              void* d_out, int out_size, void* d_ws, size_t ws_size,
                              hipStream_t stream) {
    const float* x    = (const float*)d_in[0];
    const float* W    = (const float*)d_in[1];
    const float* C    = (const float*)d_in[2];
    const float* bias = (const float*)d_in[3];
    float* out = (float*)d_out;

    char* ws = (char*)d_ws;
    char*           Pi8      = ws;                                   // 41943040
    unsigned short* Ab16     = (unsigned short*)(ws + 41943040);     // 16777216
    char*           Ci8      = ws + 58720256;                        //  5242880
    unsigned short* Wb16     = (unsigned short*)(ws + 63963136);     //  2097152
    float*          bias_aug = (float*)(ws + 66060288);              //     4096
    float*          scaleC   = (float*)(ws + 66064384);              //     4096

    hipLaunchKernelGGL(act_kernel, dim3(TOKENS * IN_F / 8 / 256), dim3(256), 0, stream,
                       x, Ab16, Pi8);
    hipLaunchKernelGGL(wt_kernel, dim3(OUT_F), dim3(256), 0, stream,
                       W, C, bias, Wb16, Ci8, scaleC, bias_aug);
    hipLaunchKernelGGL(gemm_kernel, dim3(256), dim3(256), 0, stream,
                       Pi8, Ab16, Ci8, Wb16, scaleC, bias_aug, out);
}